// Round 11
// baseline (435.524 us; speedup 1.0000x reference)
//
#include <hip/hip_runtime.h>
#include <hip/hip_bf16.h>

// HydraAttention  B=8 N=16384 C=256 NH=8 CH=32 H=W=128
// R11 = R10 GEMMs (frozen) + fused crpe (one launch, cc-split staging,
// ~34KB LDS, 4 blocks/CU) + kv_reduce grid x4 + merged prep kernel.

typedef __hip_bfloat16 bf16;
typedef __bf16 bf16x8 __attribute__((ext_vector_type(8)));
typedef unsigned short u16x8 __attribute__((ext_vector_type(8)));
typedef float f32x4 __attribute__((ext_vector_type(4)));
typedef float f32x8 __attribute__((ext_vector_type(8)));

#define SCALE_ 0.17677669529663687f

__device__ __forceinline__ unsigned short f2b(float f) {
  __hip_bfloat16 h = __float2bfloat16(f);
  return __builtin_bit_cast(unsigned short, h);
}
__device__ __forceinline__ float blo(unsigned u) {
  return __builtin_bit_cast(float, u << 16);
}
__device__ __forceinline__ float bhi(unsigned u) {
  return __builtin_bit_cast(float, u & 0xffff0000u);
}
__device__ __forceinline__ f32x8 unpack8(uint4 u) {
  f32x8 r;
  r[0] = blo(u.x); r[1] = bhi(u.x); r[2] = blo(u.y); r[3] = bhi(u.y);
  r[4] = blo(u.z); r[5] = bhi(u.z); r[6] = blo(u.w); r[7] = bhi(u.w);
  return r;
}
__device__ __forceinline__ uint4 pack8v(const f32x8 o) {
  uint4 s;
  s.x = (unsigned)f2b(o[0]) | ((unsigned)f2b(o[1]) << 16);
  s.y = (unsigned)f2b(o[2]) | ((unsigned)f2b(o[3]) << 16);
  s.z = (unsigned)f2b(o[4]) | ((unsigned)f2b(o[5]) << 16);
  s.w = (unsigned)f2b(o[6]) | ((unsigned)f2b(o[7]) << 16);
  return s;
}
__device__ __forceinline__ void gload16(const void* g, void* l) {
  __builtin_amdgcn_global_load_lds(
      (const __attribute__((address_space(1))) unsigned int*)g,
      (__attribute__((address_space(3))) unsigned int*)l, 16, 0, 0);
}
__device__ __forceinline__ f32x4 mfma16(u16x8 a, u16x8 b, f32x4 c) {
  return __builtin_amdgcn_mfma_f32_16x16x32_bf16(
      __builtin_bit_cast(bf16x8, a), __builtin_bit_cast(bf16x8, b), c, 0, 0, 0);
}
__device__ __forceinline__ void barrier_vm4() {
  asm volatile("s_waitcnt vmcnt(4) lgkmcnt(0)" ::: "memory");
  __builtin_amdgcn_s_barrier();
  asm volatile("" ::: "memory");
}
__device__ __forceinline__ void barrier_vm0() {
  asm volatile("s_waitcnt vmcnt(0) lgkmcnt(0)" ::: "memory");
  __builtin_amdgcn_s_barrier();
  asm volatile("" ::: "memory");
}
__device__ __forceinline__ void fma8(f32x8& a, const f32x8 v, const float4 w0,
                                     const float4 w1) {
  a[0] += v[0] * w0.x; a[1] += v[1] * w0.y;
  a[2] += v[2] * w0.z; a[3] += v[3] * w0.w;
  a[4] += v[4] * w1.x; a[5] += v[5] * w1.y;
  a[6] += v[6] * w1.z; a[7] += v[7] * w1.w;
}

// ------------------------------------------------------------- prep (merged)
__global__ __launch_bounds__(256) void prep_all(
    const float* __restrict__ x, const float* __restrict__ wqkv,
    const float* __restrict__ wproj, bf16* __restrict__ xb,
    bf16* __restrict__ wqkvT, bf16* __restrict__ wprojT) {
  const int bid = blockIdx.x;
  if (bid < 16384) {  // x fp32 -> bf16, 8 elems/thread
    const size_t idx = ((size_t)bid * 256 + threadIdx.x) * 8;
    const float4 a0 = *(const float4*)(x + idx);
    const float4 a1 = *(const float4*)(x + idx + 4);
    u16x8 p;
    p[0] = f2b(a0.x); p[1] = f2b(a0.y); p[2] = f2b(a0.z); p[3] = f2b(a0.w);
    p[4] = f2b(a1.x); p[5] = f2b(a1.y); p[6] = f2b(a1.z); p[7] = f2b(a1.w);
    *(u16x8*)(xb + idx) = p;
  } else {  // transposed bf16 weights
    const int idx = (bid - 16384) * 256 + threadIdx.x;
    if (idx < 768 * 256) {
      const int j = idx >> 8, k = idx & 255;
      wqkvT[idx] = __float2bfloat16(wqkv[k * 768 + j]);
    }
    if (idx < 256 * 256) {
      const int j = idx >> 8, k = idx & 255;
      wprojT[idx] = __float2bfloat16(wproj[k * 256 + j]);
    }
  }
}

// --------------------------------------------------------------- K1: qkv MFMA
// (R10, frozen) grid (6, 1024), 3-buffer LDS, 2-phase prefetch, vmcnt(4).
__global__ __launch_bounds__(256) void qkv_mfma(
    const bf16* __restrict__ xb, const bf16* __restrict__ wT,
    bf16* __restrict__ qO, bf16* __restrict__ kO, bf16* __restrict__ vO) {
  __shared__ __align__(16) char LDSU[49152];
  char* As = LDSU;
  char* Bs = LDSU + 24576;
  const int tid = threadIdx.x;
  const int l = tid & 63, w = tid >> 6;
  const int wr = w >> 1, wc = w & 1;

  const int lin = blockIdx.y * 6 + blockIdx.x;
  const int xcd = lin & 7, qq = lin >> 3;
  const int jt = qq % 6;
  const int ttile = xcd * 128 + qq / 6;
  const int j0 = jt << 7;
  const int t0 = ttile << 7;
  const int b = t0 >> 14;
  const int n0 = t0 & 16383;

  f32x4 acc[4][4];
#pragma unroll
  for (int m = 0; m < 4; ++m)
#pragma unroll
    for (int t = 0; t < 4; ++t) acc[m][t] = (f32x4){0.f, 0.f, 0.f, 0.f};

  const int row0 = w * 16 + (l >> 2), row1 = row0 + 64;
  const int sl = l & 3;
  const int sw0 = (row0 >> 1) & 3, sw1 = (row1 >> 1) & 3;
  const bf16* asrc0 = wT + (size_t)(j0 + row0) * 256 + ((sl ^ sw0) << 3);
  const bf16* asrc1 = wT + (size_t)(j0 + row1) * 256 + ((sl ^ sw1) << 3);
  const bf16* bsrc0 = xb + (size_t)(t0 + row0) * 256 + ((sl ^ sw0) << 3);
  const bf16* bsrc1 = xb + (size_t)(t0 + row1) * 256 + ((sl ^ sw1) << 3);
  const int d0 = w * 1024, d1 = 4096 + w * 1024;

  const int fr = l & 15;
  const int fq = l >> 4;
  const int fs = (fq ^ ((l >> 1) & 3)) << 4;

  gload16(asrc0, As + d0);
  gload16(asrc1, As + d1);
  gload16(bsrc0, Bs + d0);
  gload16(bsrc1, Bs + d1);
  gload16(asrc0 + 32, As + 8192 + d0);
  gload16(asrc1 + 32, As + 8192 + d1);
  gload16(bsrc0 + 32, Bs + 8192 + d0);
  gload16(bsrc1 + 32, Bs + 8192 + d1);
  barrier_vm4();

#pragma unroll
  for (int t = 0; t < 8; ++t) {
    if (t < 6) {
      const int kn = (t + 2) << 5;
      const int nb = ((t + 2) % 3) * 8192;
      gload16(asrc0 + kn, As + nb + d0);
      gload16(asrc1 + kn, As + nb + d1);
      gload16(bsrc0 + kn, Bs + nb + d0);
      gload16(bsrc1 + kn, Bs + nb + d1);
    }
    const char* Ac = As + (t % 3) * 8192;
    const char* Bc = Bs + (t % 3) * 8192;
    u16x8 af[4], bfv[4];
#pragma unroll
    for (int m = 0; m < 4; ++m)
      af[m] = *(const u16x8*)(Ac + (wr * 64 + m * 16 + fr) * 64 + fs);
#pragma unroll
    for (int tt = 0; tt < 4; ++tt)
      bfv[tt] = *(const u16x8*)(Bc + (wc * 64 + tt * 16 + fr) * 64 + fs);
    __builtin_amdgcn_s_setprio(1);
#pragma unroll
    for (int m = 0; m < 4; ++m)
#pragma unroll
      for (int tt = 0; tt < 4; ++tt)
        acc[m][tt] = mfma16(af[m], bfv[tt], acc[m][tt]);
    __builtin_amdgcn_s_setprio(0);
    if (t < 6) barrier_vm4();
    else if (t < 7) barrier_vm0();
  }
  __syncthreads();

#pragma unroll
  for (int m = 0; m < 4; ++m) {
    const int jq = wr * 16 + m * 4 + fq;
#pragma unroll
    for (int t = 0; t < 4; ++t) {
      const int token = wc * 64 + t * 16 + fr;
      const int p = jq ^ (token & 15);
      uint2 pk;
      pk.x = (unsigned)f2b(acc[m][t][0]) | ((unsigned)f2b(acc[m][t][1]) << 16);
      pk.y = (unsigned)f2b(acc[m][t][2]) | ((unsigned)f2b(acc[m][t][3]) << 16);
      *(uint2*)(LDSU + token * 256 + (p << 3)) = pk;
    }
  }
  __syncthreads();

  const int region = j0 >> 8;
  bf16* outp = (region == 0) ? qO : ((region == 1) ? kO : vO);
  const int jl = j0 & 255;
  const int seg = tid & 15;
#pragma unroll
  for (int r = 0; r < 8; ++r) {
    const int token = r * 16 + (tid >> 4);
    const int tsw = token & 15;
    const uint2 lo = *(const uint2*)(LDSU + token * 256 + (((2 * seg) ^ tsw) << 3));
    const uint2 hi =
        *(const uint2*)(LDSU + token * 256 + (((2 * seg + 1) ^ tsw) << 3));
    uint4 d;
    d.x = lo.x; d.y = lo.y; d.z = hi.x; d.w = hi.y;
    *(uint4*)&outp[((size_t)b * 16384 + n0 + token) * 256 + jl + seg * 8] = d;
  }
}

// ------------------------------------------------------------ K1b: kv reduce
// grid (256, 8): 2048 blocks (4x R10) for memory-kernel TLP.
__global__ __launch_bounds__(256) void kv_reduce(
    const bf16* __restrict__ kT, const bf16* __restrict__ vT,
    float* __restrict__ kv) {
  __shared__ float red[256 * 8];
  const int tid = threadIdx.x;
  const int b = blockIdx.y;
  const int seg = tid & 31;
  f32x8 part = (f32x8)0.f;

  for (int r = 0; r < 8; ++r) {
    const int token = blockIdx.x * 64 + r * 8 + (tid >> 5);
    const size_t roff = ((size_t)b * 16384 + token) * 256;
    const uint4 kd = *(const uint4*)(kT + roff + seg * 8);
    const f32x8 kf = unpack8(kd);
    float ss = 0.f;
#pragma unroll
    for (int i = 0; i < 8; ++i) ss += kf[i] * kf[i];
    ss += __shfl_xor(ss, 1);
    ss += __shfl_xor(ss, 2);
    const float inv = rsqrtf(ss);
    const uint4 vd = *(const uint4*)(vT + roff + seg * 8);
    const f32x8 vf = unpack8(vd);
#pragma unroll
    for (int i = 0; i < 8; ++i) part[i] += kf[i] * inv * vf[i];
  }
#pragma unroll
  for (int i = 0; i < 8; ++i) red[tid * 8 + i] = part[i];
  __syncthreads();
  if (tid < 32) {
    f32x8 s = (f32x8)0.f;
#pragma unroll
    for (int k = 0; k < 8; ++k)
#pragma unroll
      for (int i = 0; i < 8; ++i) s[i] += red[(tid + 32 * k) * 8 + i];
#pragma unroll
    for (int i = 0; i < 8; ++i)
      atomicAdd(&kv[b * 256 + seg * 8 + i], s[i]);
  }
}

// ------------------------------------------------- K2: fused crpe conv
// One launch, grid (8, 32, 8): x = head, y = 32x16 tile, z = b.
// cc-split staging: 2 channel-planes at a time -> LDS ~34KB, 4 blocks/CU.
// Conv: R8's 2px/thread rolling-register scheme.
template <int K>
__device__ __forceinline__ void crpe_impl(
    uint4* __restrict__ vs, float* __restrict__ wlds, float* __restrict__ blds,
    const bf16* __restrict__ qT, const bf16* __restrict__ vT,
    const float* __restrict__ kvbuf, const float* __restrict__ wp,
    const float* __restrict__ bp, int OC, int hg, int h,
    bf16* __restrict__ mid) {
  constexpr int R = K / 2;
  constexpr int SY = 16 + 2 * R;
  constexpr int SXr = 32 + 2 * R;
  constexpr int SX = SXr + 1;  // odd pad col
  constexpr int PL = SX * SY;
  const int tid = threadIdx.x;
  const int tile = blockIdx.y;
  const int b = blockIdx.z;
  const int tx0 = (tile & 3) * 32, ty0 = (tile >> 2) * 16;
  const int tx = tid & 15, ty = tid >> 4;
  const int ocbase = hg * 32;

  // stage weights + bias once
  for (int e = tid; e < K * K * 32; e += 256)
    wlds[e] = wp[(e >> 5) * OC + ocbase + (e & 31)];
  if (tid < 32) blds[tid] = bp[ocbase + tid];

  // q + norm
  const int n = (ty0 + ty) * 128 + tx0 + 2 * tx;
  const size_t off0 = ((size_t)b * 16384 + n) * 256 + h * 32;
  const uint4* q0 = (const uint4*)(qT + off0);
  const uint4* q1 = (const uint4*)(qT + off0 + 256);
  float ss0 = 0.f, ss1 = 0.f;
#pragma unroll
  for (int cc = 0; cc < 4; ++cc) {
    const f32x8 a = unpack8(q0[cc]);
    const f32x8 c = unpack8(q1[cc]);
#pragma unroll
    for (int i = 0; i < 8; ++i) { ss0 += a[i] * a[i]; ss1 += c[i] * c[i]; }
  }
  const float qinv0 = rsqrtf(ss0), qinv1 = rsqrtf(ss1);
  const float4* kvp = (const float4*)(kvbuf + ((size_t)b * 8 + h) * 32);
  const float4* wlds4 = (const float4*)wlds;
  const float4* bl4 = (const float4*)blds;
  uint4* m0 = (uint4*)(mid + off0);
  uint4* m1 = (uint4*)(mid + off0 + 256);

#pragma unroll 1
  for (int half = 0; half < 2; ++half) {
    __syncthreads();  // half0: weights staged; half1: prev conv reads done
    {  // stage planes cc = 2*half + {0,1}
      const int ccl = tid & 1;
      const int cc = 2 * half + ccl;
      for (int e = tid >> 1; e < SXr * SY; e += 128) {
        const int ly = e / SXr, lx = e - ly * SXr;
        const int gy = ty0 - R + ly, gx = tx0 - R + lx;
        uint4 d = {0, 0, 0, 0};
        if (gy >= 0 && gy < 128 && gx >= 0 && gx < 128)
          d = *((const uint4*)(vT + ((size_t)b * 16384 + gy * 128 + gx) * 256 +
                               h * 32) + cc);
        vs[ccl * PL + ly * SX + lx] = d;
      }
    }
    __syncthreads();
#pragma unroll
    for (int ccl = 0; ccl < 2; ++ccl) {
      const int cc = 2 * half + ccl;
      const uint4* vplane = vs + ccl * PL;
      const float4 ba = bl4[cc * 2], bb = bl4[cc * 2 + 1];
      f32x8 a0, a1;
      a0[0] = ba.x; a0[1] = ba.y; a0[2] = ba.z; a0[3] = ba.w;
      a0[4] = bb.x; a0[5] = bb.y; a0[6] = bb.z; a0[7] = bb.w;
      a1 = a0;
#pragma unroll
      for (int ky = 0; ky < K; ++ky) {
        const uint4* vrow = vplane + (ty + ky) * SX + 2 * tx;
        f32x8 vcur = unpack8(vrow[0]);
#pragma unroll
        for (int kx = 0; kx < K; ++kx) {
          const f32x8 vnx = unpack8(vrow[kx + 1]);
          const float4 w0 = wlds4[(ky * K + kx) * 8 + cc * 2];
          const float4 w1 = wlds4[(ky * K + kx) * 8 + cc * 2 + 1];
          fma8(a0, vcur, w0, w1);
          fma8(a1, vnx, w0, w1);
          vcur = vnx;
        }
      }
      const float4 ka = kvp[cc * 2], kb = kvp[cc * 2 + 1];
      f32x8 kvf;
      kvf[0] = ka.x; kvf[1] = ka.y; kvf[2] = ka.z; kvf[3] = ka.w;
      kvf[4] = kb.x; kvf[5] = kb.y; kvf[6] = kb.z; kvf[7] = kb.w;
      {
        const f32x8 qv = unpack8(q0[cc]);
        f32x8 o;
#pragma unroll
        for (int i = 0; i < 8; ++i)
          o[i] = SCALE_ * qv[i] * qinv0 * kvf[i] + qv[i] * a0[i];
        m0[cc] = pack8v(o);
      }
      {
        const f32x8 qv = unpack8(q1[cc]);
        f32x8 o;
#pragma unroll
        for (int i = 0; i < 8; ++i)
          o[i] = SCALE_ * qv[i] * qinv1 * kvf[i] + qv[i] * a1[i];
        m1[cc] = pack8v(o);
      }
    }
  }
}

__global__ __launch_bounds__(256) void crpe_all(
    const bf16* __restrict__ qT, const bf16* __restrict__ vT,
    const float* __restrict__ kvbuf,
    const float* __restrict__ w3, const float* __restrict__ b3,
    const float* __restrict__ w5, const float* __restrict__ b5,
    const float* __restrict__ w7, const float* __restrict__ b7,
    bf16* __restrict__ mid) {
  // sized for K=7: 2 planes x (39*22) uint4 = 27.5KB + 6.3KB weights
  __shared__ __align__(16) uint4 vs[2 * 39 * 22];
  __shared__ float wlds[49 * 32];
  __shared__ float blds[32];
  const int h = blockIdx.x;
  if (h < 2)
    crpe_impl<3>(vs, wlds, blds, qT, vT, kvbuf, w3, b3, 64, h, h, mid);
  else if (h < 5)
    crpe_impl<5>(vs, wlds, blds, qT, vT, kvbuf, w5, b5, 96, h - 2, h, mid);
  else
    crpe_impl<7>(vs, wlds, blds, qT, vT, kvbuf, w7, b7, 96, h - 5, h, mid);
}

// --------------------------------------------------------------- K3: proj MFMA
// (R10, frozen)
__global__ __launch_bounds__(256) void proj_mfma(
    const bf16* __restrict__ mid, const bf16* __restrict__ wpT,
    const float* __restrict__ bproj, float* __restrict__ out) {
  __shared__ __align__(16) char LDSU[49152];
  char* As = LDSU;
  char* Bs = LDSU + 24576;
  const int tid = threadIdx.x;
  const int l = tid & 63, w = tid >> 6;
  const int wr = w >> 1, wc = w & 1;

  const int lin = blockIdx.y * 2 + blockIdx.x;
  const int xcd = lin & 7, qq = lin >> 3;
  const int jt = qq & 1;
  const int ttile = xcd * 128 + (qq >> 1);
  const int j0 = jt << 7;
  const int tk0 = ttile << 7;

  f32x4 acc[4][4];
#pragma unroll
  for (int m = 0; m < 4; ++m)
#pragma unroll
    for (int t = 0; t < 4; ++t) acc[m][t] = (f32x4){0.f, 0.f, 0.f, 0.f};

  const int row0 = w * 16 + (l >> 2), row1 = row0 + 64;
  const int sl = l & 3;
  const int sw0 = (row0 >> 1) & 3, sw1 = (row1 >> 1) & 3;
  const bf16* asrc0 = wpT + (size_t)(j0 + row0) * 256 + ((sl ^ sw0) << 3);
  const bf16* asrc1 = wpT + (size_t)(j0 + row1) * 256 + ((sl ^ sw1) << 3);
  const bf16* bsrc0 = mid + (size_t)(tk0 + row0) * 256 + ((sl ^ sw0) << 3);
  const bf16* bsrc1 = mid + (size_t)(tk0 + row1) * 256 + ((sl ^ sw1) << 3);
  const int d0 = w * 1024, d1 = 4096 + w * 1024;

  const int fr = l & 15;
  const int fq = l >> 4;
  const int fs = (fq ^ ((l >> 1) & 3)) << 4;

  gload16(asrc0, As + d0);
  gload16(asrc1, As + d1);
  gload16(bsrc0, Bs + d0);
  gload16(bsrc1, Bs + d1);
  gload16(asrc0 + 32, As + 8192 + d0);
  gload16(asrc1 + 32, As + 8192 + d1);
  gload16(bsrc0 + 32, Bs + 8192 + d0);
  gload16(bsrc1 + 32, Bs + 8192 + d1);
  barrier_vm4();

#pragma unroll
  for (int t = 0; t < 8; ++t) {
    if (t < 6) {
      const int kn = (t + 2) << 5;
      const int nb = ((t + 2) % 3) * 8192;
      gload16(asrc0 + kn, As + nb + d0);
      gload16(asrc1 + kn, As + nb + d1);
      gload16(bsrc0 + kn, Bs + nb + d0);
      gload16(bsrc1 + kn, Bs + nb + d1);
    }
    const char* Ac = As + (t % 3) * 8192;
    const char* Bc = Bs + (t % 3) * 8192;
    u16x8 af[4], bfv[4];
#pragma unroll
    for (int m = 0; m < 4; ++m)
      af[m] = *(const u16x8*)(Ac + (wr * 64 + m * 16 + fr) * 64 + fs);
#pragma unroll
    for (int tt = 0; tt < 4; ++tt)
      bfv[tt] = *(const u16x8*)(Bc + (wc * 64 + tt * 16 + fr) * 64 + fs);
    __builtin_amdgcn_s_setprio(1);
#pragma unroll
    for (int m = 0; m < 4; ++m)
#pragma unroll
      for (int tt = 0; tt < 4; ++tt)
        acc[m][tt] = mfma16(af[m], bfv[tt], acc[m][tt]);
    __builtin_amdgcn_s_setprio(0);
    if (t < 6) barrier_vm4();
    else if (t < 7) barrier_vm0();
  }
  __syncthreads();

#pragma unroll
  for (int m = 0; m < 4; ++m) {
    const float4 bias = *(const float4*)&bproj[j0 + wr * 64 + m * 16 + fq * 4];
#pragma unroll
    for (int t = 0; t < 4; ++t) {
      acc[m][t][0] += bias.x;
      acc[m][t][1] += bias.y;
      acc[m][t][2] += bias.z;
      acc[m][t][3] += bias.w;
    }
  }

  for (int chunk = 0; chunk < 2; ++chunk) {
    if (wc == chunk) {
#pragma unroll
      for (int m = 0; m < 4; ++m) {
        const int jq = wr * 16 + m * 4 + fq;
#pragma unroll
        for (int t = 0; t < 4; ++t) {
          const int ltok = t * 16 + fr;
          const int p = jq ^ (ltok & 15);
          float4 r;
          r.x = acc[m][t][0]; r.y = acc[m][t][1];
          r.z = acc[m][t][2]; r.w = acc[m][t][3];
          *(float4*)(LDSU + ltok * 512 + (p << 4)) = r;
        }
      }
    }
    __syncthreads();
    const int seg = tid & 31;
#pragma unroll
    for (int r = 0; r < 8; ++r) {
      const int ltok = r * 8 + (tid >> 5);
      const int p = seg ^ (ltok & 15);
      const float4 dv = *(const float4*)(LDSU + ltok * 512 + (p << 4));
      *(float4*)&out[(size_t)(tk0 + chunk * 64 + ltok) * 256 + j0 + seg * 4] = dv;
    }
    __syncthreads();
  }
}

// ------------------------------------------------------------------- launcher
extern "C" void kernel_launch(void* const* d_in, const int* in_sizes, int n_in,
                              void* d_out, int out_size, void* d_ws,
                              size_t ws_size, hipStream_t stream) {
  const float* x     = (const float*)d_in[0];
  const float* wqkv  = (const float*)d_in[1];
  const float* wproj = (const float*)d_in[2];
  const float* bproj = (const float*)d_in[3];
  const float* w3 = (const float*)d_in[4];
  const float* b3 = (const float*)d_in[5];
  const float* w5 = (const float*)d_in[6];
  const float* b5 = (const float*)d_in[7];
  const float* w7 = (const float*)d_in[8];
  const float* b7 = (const float*)d_in[9];
  float* out = (float*)d_out;

  const size_t PLANE = (size_t)8 * 16384 * 256;
  bf16* qT  = (bf16*)d_ws;
  bf16* vT  = qT + PLANE;
  bf16* kT  = vT + PLANE;
  bf16* mid = kT;                     // alias: k dead after kv_reduce
  float* kv = (float*)(kT + PLANE);
  bf16* wqkvT  = (bf16*)(kv + 2048);
  bf16* wprojT = wqkvT + 768 * 256;
  bf16* xb = (bf16*)d_out;            // scratch until proj overwrites

  hipMemsetAsync(kv, 0, 2048 * sizeof(float), stream);
  prep_all<<<dim3(16384 + 768), 256, 0, stream>>>(x, wqkv, wproj, xb, wqkvT,
                                                  wprojT);
  qkv_mfma<<<dim3(6, 1024), 256, 0, stream>>>(xb, wqkvT, qT, kT, vT);
  kv_reduce<<<dim3(256, 8), 256, 0, stream>>>(kT, vT, kv);
  crpe_all<<<dim3(8, 32, 8), 256, 0, stream>>>(qT, vT, kv, w3, b3, w5, b5, w7,
                                               b7, mid);
  proj_mfma<<<dim3(2, 1024), 256, 0, stream>>>(mid, wprojT, bproj, out);
}

// Round 12
// 400.080 us; speedup vs baseline: 1.0886x; 1.0886x over previous
//
#include <hip/hip_runtime.h>
#include <hip/hip_bf16.h>

// HydraAttention  B=8 N=16384 C=256 NH=8 CH=32 H=W=128
// R12 = R10 GEMMs (frozen) + R8 template crpe with full-line store epilogue
// (pack all 4 cc results in regs -> out-LDS (reuses v planes) -> cooperative
// lane=(px,cc) stores = complete 64B lines) + merged prep + kv grid (256,8).

typedef __hip_bfloat16 bf16;
typedef __bf16 bf16x8 __attribute__((ext_vector_type(8)));
typedef unsigned short u16x8 __attribute__((ext_vector_type(8)));
typedef float f32x4 __attribute__((ext_vector_type(4)));
typedef float f32x8 __attribute__((ext_vector_type(8)));

#define SCALE_ 0.17677669529663687f

__device__ __forceinline__ unsigned short f2b(float f) {
  __hip_bfloat16 h = __float2bfloat16(f);
  return __builtin_bit_cast(unsigned short, h);
}
__device__ __forceinline__ float blo(unsigned u) {
  return __builtin_bit_cast(float, u << 16);
}
__device__ __forceinline__ float bhi(unsigned u) {
  return __builtin_bit_cast(float, u & 0xffff0000u);
}
__device__ __forceinline__ f32x8 unpack8(uint4 u) {
  f32x8 r;
  r[0] = blo(u.x); r[1] = bhi(u.x); r[2] = blo(u.y); r[3] = bhi(u.y);
  r[4] = blo(u.z); r[5] = bhi(u.z); r[6] = blo(u.w); r[7] = bhi(u.w);
  return r;
}
__device__ __forceinline__ uint4 pack8v(const f32x8 o) {
  uint4 s;
  s.x = (unsigned)f2b(o[0]) | ((unsigned)f2b(o[1]) << 16);
  s.y = (unsigned)f2b(o[2]) | ((unsigned)f2b(o[3]) << 16);
  s.z = (unsigned)f2b(o[4]) | ((unsigned)f2b(o[5]) << 16);
  s.w = (unsigned)f2b(o[6]) | ((unsigned)f2b(o[7]) << 16);
  return s;
}
__device__ __forceinline__ void gload16(const void* g, void* l) {
  __builtin_amdgcn_global_load_lds(
      (const __attribute__((address_space(1))) unsigned int*)g,
      (__attribute__((address_space(3))) unsigned int*)l, 16, 0, 0);
}
__device__ __forceinline__ f32x4 mfma16(u16x8 a, u16x8 b, f32x4 c) {
  return __builtin_amdgcn_mfma_f32_16x16x32_bf16(
      __builtin_bit_cast(bf16x8, a), __builtin_bit_cast(bf16x8, b), c, 0, 0, 0);
}
__device__ __forceinline__ void barrier_vm4() {
  asm volatile("s_waitcnt vmcnt(4) lgkmcnt(0)" ::: "memory");
  __builtin_amdgcn_s_barrier();
  asm volatile("" ::: "memory");
}
__device__ __forceinline__ void barrier_vm0() {
  asm volatile("s_waitcnt vmcnt(0) lgkmcnt(0)" ::: "memory");
  __builtin_amdgcn_s_barrier();
  asm volatile("" ::: "memory");
}
__device__ __forceinline__ void fma8(f32x8& a, const f32x8 v, const float4 w0,
                                     const float4 w1) {
  a[0] += v[0] * w0.x; a[1] += v[1] * w0.y;
  a[2] += v[2] * w0.z; a[3] += v[3] * w0.w;
  a[4] += v[4] * w1.x; a[5] += v[5] * w1.y;
  a[6] += v[6] * w1.z; a[7] += v[7] * w1.w;
}

// ------------------------------------------------------------- prep (merged)
__global__ __launch_bounds__(256) void prep_all(
    const float* __restrict__ x, const float* __restrict__ wqkv,
    const float* __restrict__ wproj, bf16* __restrict__ xb,
    bf16* __restrict__ wqkvT, bf16* __restrict__ wprojT) {
  const int bid = blockIdx.x;
  if (bid < 16384) {
    const size_t idx = ((size_t)bid * 256 + threadIdx.x) * 8;
    const float4 a0 = *(const float4*)(x + idx);
    const float4 a1 = *(const float4*)(x + idx + 4);
    u16x8 p;
    p[0] = f2b(a0.x); p[1] = f2b(a0.y); p[2] = f2b(a0.z); p[3] = f2b(a0.w);
    p[4] = f2b(a1.x); p[5] = f2b(a1.y); p[6] = f2b(a1.z); p[7] = f2b(a1.w);
    *(u16x8*)(xb + idx) = p;
  } else {
    const int idx = (bid - 16384) * 256 + threadIdx.x;
    if (idx < 768 * 256) {
      const int j = idx >> 8, k = idx & 255;
      wqkvT[idx] = __float2bfloat16(wqkv[k * 768 + j]);
    }
    if (idx < 256 * 256) {
      const int j = idx >> 8, k = idx & 255;
      wprojT[idx] = __float2bfloat16(wproj[k * 256 + j]);
    }
  }
}

// --------------------------------------------------------------- K1: qkv MFMA
// (R10, frozen)
__global__ __launch_bounds__(256) void qkv_mfma(
    const bf16* __restrict__ xb, const bf16* __restrict__ wT,
    bf16* __restrict__ qO, bf16* __restrict__ kO, bf16* __restrict__ vO) {
  __shared__ __align__(16) char LDSU[49152];
  char* As = LDSU;
  char* Bs = LDSU + 24576;
  const int tid = threadIdx.x;
  const int l = tid & 63, w = tid >> 6;
  const int wr = w >> 1, wc = w & 1;

  const int lin = blockIdx.y * 6 + blockIdx.x;
  const int xcd = lin & 7, qq = lin >> 3;
  const int jt = qq % 6;
  const int ttile = xcd * 128 + qq / 6;
  const int j0 = jt << 7;
  const int t0 = ttile << 7;
  const int b = t0 >> 14;
  const int n0 = t0 & 16383;

  f32x4 acc[4][4];
#pragma unroll
  for (int m = 0; m < 4; ++m)
#pragma unroll
    for (int t = 0; t < 4; ++t) acc[m][t] = (f32x4){0.f, 0.f, 0.f, 0.f};

  const int row0 = w * 16 + (l >> 2), row1 = row0 + 64;
  const int sl = l & 3;
  const int sw0 = (row0 >> 1) & 3, sw1 = (row1 >> 1) & 3;
  const bf16* asrc0 = wT + (size_t)(j0 + row0) * 256 + ((sl ^ sw0) << 3);
  const bf16* asrc1 = wT + (size_t)(j0 + row1) * 256 + ((sl ^ sw1) << 3);
  const bf16* bsrc0 = xb + (size_t)(t0 + row0) * 256 + ((sl ^ sw0) << 3);
  const bf16* bsrc1 = xb + (size_t)(t0 + row1) * 256 + ((sl ^ sw1) << 3);
  const int d0 = w * 1024, d1 = 4096 + w * 1024;

  const int fr = l & 15;
  const int fq = l >> 4;
  const int fs = (fq ^ ((l >> 1) & 3)) << 4;

  gload16(asrc0, As + d0);
  gload16(asrc1, As + d1);
  gload16(bsrc0, Bs + d0);
  gload16(bsrc1, Bs + d1);
  gload16(asrc0 + 32, As + 8192 + d0);
  gload16(asrc1 + 32, As + 8192 + d1);
  gload16(bsrc0 + 32, Bs + 8192 + d0);
  gload16(bsrc1 + 32, Bs + 8192 + d1);
  barrier_vm4();

#pragma unroll
  for (int t = 0; t < 8; ++t) {
    if (t < 6) {
      const int kn = (t + 2) << 5;
      const int nb = ((t + 2) % 3) * 8192;
      gload16(asrc0 + kn, As + nb + d0);
      gload16(asrc1 + kn, As + nb + d1);
      gload16(bsrc0 + kn, Bs + nb + d0);
      gload16(bsrc1 + kn, Bs + nb + d1);
    }
    const char* Ac = As + (t % 3) * 8192;
    const char* Bc = Bs + (t % 3) * 8192;
    u16x8 af[4], bfv[4];
#pragma unroll
    for (int m = 0; m < 4; ++m)
      af[m] = *(const u16x8*)(Ac + (wr * 64 + m * 16 + fr) * 64 + fs);
#pragma unroll
    for (int tt = 0; tt < 4; ++tt)
      bfv[tt] = *(const u16x8*)(Bc + (wc * 64 + tt * 16 + fr) * 64 + fs);
    __builtin_amdgcn_s_setprio(1);
#pragma unroll
    for (int m = 0; m < 4; ++m)
#pragma unroll
      for (int tt = 0; tt < 4; ++tt)
        acc[m][tt] = mfma16(af[m], bfv[tt], acc[m][tt]);
    __builtin_amdgcn_s_setprio(0);
    if (t < 6) barrier_vm4();
    else if (t < 7) barrier_vm0();
  }
  __syncthreads();

#pragma unroll
  for (int m = 0; m < 4; ++m) {
    const int jq = wr * 16 + m * 4 + fq;
#pragma unroll
    for (int t = 0; t < 4; ++t) {
      const int token = wc * 64 + t * 16 + fr;
      const int p = jq ^ (token & 15);
      uint2 pk;
      pk.x = (unsigned)f2b(acc[m][t][0]) | ((unsigned)f2b(acc[m][t][1]) << 16);
      pk.y = (unsigned)f2b(acc[m][t][2]) | ((unsigned)f2b(acc[m][t][3]) << 16);
      *(uint2*)(LDSU + token * 256 + (p << 3)) = pk;
    }
  }
  __syncthreads();

  const int region = j0 >> 8;
  bf16* outp = (region == 0) ? qO : ((region == 1) ? kO : vO);
  const int jl = j0 & 255;
  const int seg = tid & 15;
#pragma unroll
  for (int r = 0; r < 8; ++r) {
    const int token = r * 16 + (tid >> 4);
    const int tsw = token & 15;
    const uint2 lo = *(const uint2*)(LDSU + token * 256 + (((2 * seg) ^ tsw) << 3));
    const uint2 hi =
        *(const uint2*)(LDSU + token * 256 + (((2 * seg + 1) ^ tsw) << 3));
    uint4 d;
    d.x = lo.x; d.y = lo.y; d.z = hi.x; d.w = hi.y;
    *(uint4*)&outp[((size_t)b * 16384 + n0 + token) * 256 + jl + seg * 8] = d;
  }
}

// ------------------------------------------------------------ K1b: kv reduce
__global__ __launch_bounds__(256) void kv_reduce(
    const bf16* __restrict__ kT, const bf16* __restrict__ vT,
    float* __restrict__ kv) {
  __shared__ float red[256 * 8];
  const int tid = threadIdx.x;
  const int b = blockIdx.y;
  const int seg = tid & 31;
  f32x8 part = (f32x8)0.f;

  for (int r = 0; r < 8; ++r) {
    const int token = blockIdx.x * 64 + r * 8 + (tid >> 5);
    const size_t roff = ((size_t)b * 16384 + token) * 256;
    const uint4 kd = *(const uint4*)(kT + roff + seg * 8);
    const f32x8 kf = unpack8(kd);
    float ss = 0.f;
#pragma unroll
    for (int i = 0; i < 8; ++i) ss += kf[i] * kf[i];
    ss += __shfl_xor(ss, 1);
    ss += __shfl_xor(ss, 2);
    const float inv = rsqrtf(ss);
    const uint4 vd = *(const uint4*)(vT + roff + seg * 8);
    const f32x8 vf = unpack8(vd);
#pragma unroll
    for (int i = 0; i < 8; ++i) part[i] += kf[i] * inv * vf[i];
  }
#pragma unroll
  for (int i = 0; i < 8; ++i) red[tid * 8 + i] = part[i];
  __syncthreads();
  if (tid < 32) {
    f32x8 s = (f32x8)0.f;
#pragma unroll
    for (int k = 0; k < 8; ++k)
#pragma unroll
      for (int i = 0; i < 8; ++i) s[i] += red[(tid + 32 * k) * 8 + i];
#pragma unroll
    for (int i = 0; i < 8; ++i)
      atomicAdd(&kv[b * 256 + seg * 8 + i], s[i]);
  }
}

// ------------------------------------------------- K2: crpe conv + combine
// R8 interior (full 64B staging, 2px rolling conv) + full-line store
// epilogue: cc loop fully unrolled, packed results -> out-LDS (reuses v
// planes) -> cooperative lane=(px,cc) stores (16 complete 64B lines/inst).
template <int K>
__global__ __launch_bounds__(256) void crpe_conv(
    const bf16* __restrict__ qT, const bf16* __restrict__ vT,
    const float* __restrict__ kvbuf, const float* __restrict__ wp,
    const float* __restrict__ bp, int OC, int hbase,
    bf16* __restrict__ mid) {
  constexpr int R = K / 2;
  constexpr int SY = 16 + 2 * R;
  constexpr int SXr = 32 + 2 * R;
  constexpr int SX = SXr + 1;  // odd pad col
  constexpr int PL = SX * SY;
  __shared__ __align__(16) uint4 vs[4 * PL];  // >= 2048 for out staging (K3 min: 2520)
  __shared__ float wlds[K * K * 32];
  __shared__ float blds[32];

  const int tid = threadIdx.x;
  const int hg = blockIdx.x;
  const int h = hbase + hg;
  const int tile = blockIdx.y;
  const int b = blockIdx.z;
  const int tx0 = (tile & 3) * 32, ty0 = (tile >> 2) * 16;
  const int tx = tid & 15, ty = tid >> 4;
  const int ocbase = hg * 32;

  {  // stage v tile+halo, full 64B per pixel, plane-per-cc
    const int cc = tid & 3;
    for (int e = tid >> 2; e < SXr * SY; e += 64) {
      const int ly = e / SXr, lx = e - ly * SXr;
      const int gy = ty0 - R + ly, gx = tx0 - R + lx;
      uint4 d = {0, 0, 0, 0};
      if (gy >= 0 && gy < 128 && gx >= 0 && gx < 128)
        d = *((const uint4*)(vT + ((size_t)b * 16384 + gy * 128 + gx) * 256 +
                             h * 32) + cc);
      vs[cc * PL + ly * SX + lx] = d;
    }
  }
  for (int e = tid; e < K * K * 32; e += 256)
    wlds[e] = wp[(e >> 5) * OC + ocbase + (e & 31)];
  if (tid < 32) blds[tid] = bp[ocbase + tid];
  __syncthreads();

  const int n = (ty0 + ty) * 128 + tx0 + 2 * tx;
  const size_t off0 = ((size_t)b * 16384 + n) * 256 + h * 32;
  const uint4* q0 = (const uint4*)(qT + off0);
  const uint4* q1 = (const uint4*)(qT + off0 + 256);
  float ss0 = 0.f, ss1 = 0.f;
#pragma unroll
  for (int cc = 0; cc < 4; ++cc) {
    const f32x8 a = unpack8(q0[cc]);
    const f32x8 c = unpack8(q1[cc]);
#pragma unroll
    for (int i = 0; i < 8; ++i) { ss0 += a[i] * a[i]; ss1 += c[i] * c[i]; }
  }
  const float qinv0 = rsqrtf(ss0), qinv1 = rsqrtf(ss1);
  const float4* kvp = (const float4*)(kvbuf + ((size_t)b * 8 + h) * 32);
  const float4* wlds4 = (const float4*)wlds;
  const float4* bl4 = (const float4*)blds;

  uint4 po0[4], po1[4];  // packed bf16 results per px (literal cc indices)
#pragma unroll
  for (int cc = 0; cc < 4; ++cc) {
    const uint4* vplane = vs + cc * PL;
    const float4 ba = bl4[cc * 2], bb = bl4[cc * 2 + 1];
    f32x8 a0, a1;
    a0[0] = ba.x; a0[1] = ba.y; a0[2] = ba.z; a0[3] = ba.w;
    a0[4] = bb.x; a0[5] = bb.y; a0[6] = bb.z; a0[7] = bb.w;
    a1 = a0;
#pragma unroll
    for (int ky = 0; ky < K; ++ky) {
      const uint4* vrow = vplane + (ty + ky) * SX + 2 * tx;
      f32x8 vcur = unpack8(vrow[0]);
#pragma unroll
      for (int kx = 0; kx < K; ++kx) {
        const f32x8 vnx = unpack8(vrow[kx + 1]);
        const float4 w0 = wlds4[(ky * K + kx) * 8 + cc * 2];
        const float4 w1 = wlds4[(ky * K + kx) * 8 + cc * 2 + 1];
        fma8(a0, vcur, w0, w1);
        fma8(a1, vnx, w0, w1);
        vcur = vnx;
      }
    }
    const float4 ka = kvp[cc * 2], kb = kvp[cc * 2 + 1];
    f32x8 kvf;
    kvf[0] = ka.x; kvf[1] = ka.y; kvf[2] = ka.z; kvf[3] = ka.w;
    kvf[4] = kb.x; kvf[5] = kb.y; kvf[6] = kb.z; kvf[7] = kb.w;
    {
      const f32x8 qv = unpack8(q0[cc]);
      f32x8 o;
#pragma unroll
      for (int i = 0; i < 8; ++i)
        o[i] = SCALE_ * qv[i] * qinv0 * kvf[i] + qv[i] * a0[i];
      po0[cc] = pack8v(o);
    }
    {
      const f32x8 qv = unpack8(q1[cc]);
      f32x8 o;
#pragma unroll
      for (int i = 0; i < 8; ++i)
        o[i] = SCALE_ * qv[i] * qinv1 * kvf[i] + qv[i] * a1[i];
      po1[cc] = pack8v(o);
    }
  }

  // ---- full-line store epilogue: stage 512px x 64B into vs (v is dead)
  __syncthreads();  // all conv LDS reads complete
  const int p0 = ty * 32 + 2 * tx, p1 = p0 + 1;
#pragma unroll
  for (int cc = 0; cc < 4; ++cc) {
    vs[p0 * 4 + (cc ^ (p0 & 3))] = po0[cc];
    vs[p1 * 4 + (cc ^ (p1 & 3))] = po1[cc];
  }
  __syncthreads();
  const size_t tbase = ((size_t)b * 16384) * 256 + h * 32;
#pragma unroll
  for (int r = 0; r < 8; ++r) {
    const int gid = r * 256 + tid;
    const int px = gid >> 2, cc = gid & 3;
    const int py = px >> 5, pxx = px & 31;
    const int nn = (ty0 + py) * 128 + tx0 + pxx;
    const uint4 d = vs[px * 4 + (cc ^ (px & 3))];
    *((uint4*)(mid + tbase + (size_t)nn * 256) + cc) = d;
  }
}

// --------------------------------------------------------------- K3: proj MFMA
// (R10, frozen)
__global__ __launch_bounds__(256) void proj_mfma(
    const bf16* __restrict__ mid, const bf16* __restrict__ wpT,
    const float* __restrict__ bproj, float* __restrict__ out) {
  __shared__ __align__(16) char LDSU[49152];
  char* As = LDSU;
  char* Bs = LDSU + 24576;
  const int tid = threadIdx.x;
  const int l = tid & 63, w = tid >> 6;
  const int wr = w >> 1, wc = w & 1;

  const int lin = blockIdx.y * 2 + blockIdx.x;
  const int xcd = lin & 7, qq = lin >> 3;
  const int jt = qq & 1;
  const int ttile = xcd * 128 + (qq >> 1);
  const int j0 = jt << 7;
  const int tk0 = ttile << 7;

  f32x4 acc[4][4];
#pragma unroll
  for (int m = 0; m < 4; ++m)
#pragma unroll
    for (int t = 0; t < 4; ++t) acc[m][t] = (f32x4){0.f, 0.f, 0.f, 0.f};

  const int row0 = w * 16 + (l >> 2), row1 = row0 + 64;
  const int sl = l & 3;
  const int sw0 = (row0 >> 1) & 3, sw1 = (row1 >> 1) & 3;
  const bf16* asrc0 = wpT + (size_t)(j0 + row0) * 256 + ((sl ^ sw0) << 3);
  const bf16* asrc1 = wpT + (size_t)(j0 + row1) * 256 + ((sl ^ sw1) << 3);
  const bf16* bsrc0 = mid + (size_t)(tk0 + row0) * 256 + ((sl ^ sw0) << 3);
  const bf16* bsrc1 = mid + (size_t)(tk0 + row1) * 256 + ((sl ^ sw1) << 3);
  const int d0 = w * 1024, d1 = 4096 + w * 1024;

  const int fr = l & 15;
  const int fq = l >> 4;
  const int fs = (fq ^ ((l >> 1) & 3)) << 4;

  gload16(asrc0, As + d0);
  gload16(asrc1, As + d1);
  gload16(bsrc0, Bs + d0);
  gload16(bsrc1, Bs + d1);
  gload16(asrc0 + 32, As + 8192 + d0);
  gload16(asrc1 + 32, As + 8192 + d1);
  gload16(bsrc0 + 32, Bs + 8192 + d0);
  gload16(bsrc1 + 32, Bs + 8192 + d1);
  barrier_vm4();

#pragma unroll
  for (int t = 0; t < 8; ++t) {
    if (t < 6) {
      const int kn = (t + 2) << 5;
      const int nb = ((t + 2) % 3) * 8192;
      gload16(asrc0 + kn, As + nb + d0);
      gload16(asrc1 + kn, As + nb + d1);
      gload16(bsrc0 + kn, Bs + nb + d0);
      gload16(bsrc1 + kn, Bs + nb + d1);
    }
    const char* Ac = As + (t % 3) * 8192;
    const char* Bc = Bs + (t % 3) * 8192;
    u16x8 af[4], bfv[4];
#pragma unroll
    for (int m = 0; m < 4; ++m)
      af[m] = *(const u16x8*)(Ac + (wr * 64 + m * 16 + fr) * 64 + fs);
#pragma unroll
    for (int tt = 0; tt < 4; ++tt)
      bfv[tt] = *(const u16x8*)(Bc + (wc * 64 + tt * 16 + fr) * 64 + fs);
    __builtin_amdgcn_s_setprio(1);
#pragma unroll
    for (int m = 0; m < 4; ++m)
#pragma unroll
      for (int tt = 0; tt < 4; ++tt)
        acc[m][tt] = mfma16(af[m], bfv[tt], acc[m][tt]);
    __builtin_amdgcn_s_setprio(0);
    if (t < 6) barrier_vm4();
    else if (t < 7) barrier_vm0();
  }
  __syncthreads();

#pragma unroll
  for (int m = 0; m < 4; ++m) {
    const float4 bias = *(const float4*)&bproj[j0 + wr * 64 + m * 16 + fq * 4];
#pragma unroll
    for (int t = 0; t < 4; ++t) {
      acc[m][t][0] += bias.x;
      acc[m][t][1] += bias.y;
      acc[m][t][2] += bias.z;
      acc[m][t][3] += bias.w;
    }
  }

  for (int chunk = 0; chunk < 2; ++chunk) {
    if (wc == chunk) {
#pragma unroll
      for (int m = 0; m < 4; ++m) {
        const int jq = wr * 16 + m * 4 + fq;
#pragma unroll
        for (int t = 0; t < 4; ++t) {
          const int ltok = t * 16 + fr;
          const int p = jq ^ (ltok & 15);
          float4 r;
          r.x = acc[m][t][0]; r.y = acc[m][t][1];
          r.z = acc[m][t][2]; r.w = acc[m][t][3];
          *(float4*)(LDSU + ltok * 512 + (p << 4)) = r;
        }
      }
    }
    __syncthreads();
    const int seg = tid & 31;
#pragma unroll
    for (int r = 0; r < 8; ++r) {
      const int ltok = r * 8 + (tid >> 5);
      const int p = seg ^ (ltok & 15);
      const float4 dv = *(const float4*)(LDSU + ltok * 512 + (p << 4));
      *(float4*)&out[(size_t)(tk0 + chunk * 64 + ltok) * 256 + j0 + seg * 4] = dv;
    }
    __syncthreads();
  }
}

// ------------------------------------------------------------------- launcher
extern "C" void kernel_launch(void* const* d_in, const int* in_sizes, int n_in,
                              void* d_out, int out_size, void* d_ws,
                              size_t ws_size, hipStream_t stream) {
  const float* x     = (const float*)d_in[0];
  const float* wqkv  = (const float*)d_in[1];
  const float* wproj = (const float*)d_in[2];
  const float* bproj = (const float*)d_in[3];
  const float* w3 = (const float*)d_in[4];
  const float* b3 = (const float*)d_in[5];
  const float* w5 = (const float*)d_in[6];
  const float* b5 = (const float*)d_in[7];
  const float* w7 = (const float*)d_in[8];
  const float* b7 = (const float*)d_in[9];
  float* out = (float*)d_out;

  const size_t PLANE = (size_t)8 * 16384 * 256;
  bf16* qT  = (bf16*)d_ws;
  bf16* vT  = qT + PLANE;
  bf16* kT  = vT + PLANE;
  bf16* mid = kT;                     // alias: k dead after kv_reduce
  float* kv = (float*)(kT + PLANE);
  bf16* wqkvT  = (bf16*)(kv + 2048);
  bf16* wprojT = wqkvT + 768 * 256;
  bf16* xb = (bf16*)d_out;            // scratch until proj overwrites

  hipMemsetAsync(kv, 0, 2048 * sizeof(float), stream);
  prep_all<<<dim3(16384 + 768), 256, 0, stream>>>(x, wqkv, wproj, xb, wqkvT,
                                                  wprojT);
  qkv_mfma<<<dim3(6, 1024), 256, 0, stream>>>(xb, wqkvT, qT, kT, vT);
  kv_reduce<<<dim3(256, 8), 256, 0, stream>>>(kT, vT, kv);
  crpe_conv<3><<<dim3(2, 32, 8), 256, 0, stream>>>(qT, vT, kv, w3, b3, 64, 0, mid);
  crpe_conv<5><<<dim3(3, 32, 8), 256, 0, stream>>>(qT, vT, kv, w5, b5, 96, 2, mid);
  crpe_conv<7><<<dim3(3, 32, 8), 256, 0, stream>>>(qT, vT, kv, w7, b7, 96, 5, mid);
  proj_mfma<<<dim3(2, 1024), 256, 0, stream>>>(mid, wprojT, bproj, out);
}

// Round 13
// 348.310 us; speedup vs baseline: 1.2504x; 1.1486x over previous
//
#include <hip/hip_runtime.h>
#include <hip/hip_bf16.h>

// HydraAttention  B=8 N=16384 C=256 NH=8 CH=32 H=W=128
// R13 = R10 GEMMs (frozen) + R8/R10 crpe (direct stores) + two-stage
// atomic-free kv reduction (partials in d_out dead region) + merged prep.

typedef __hip_bfloat16 bf16;
typedef __bf16 bf16x8 __attribute__((ext_vector_type(8)));
typedef unsigned short u16x8 __attribute__((ext_vector_type(8)));
typedef float f32x4 __attribute__((ext_vector_type(4)));
typedef float f32x8 __attribute__((ext_vector_type(8)));

#define SCALE_ 0.17677669529663687f

__device__ __forceinline__ unsigned short f2b(float f) {
  __hip_bfloat16 h = __float2bfloat16(f);
  return __builtin_bit_cast(unsigned short, h);
}
__device__ __forceinline__ float blo(unsigned u) {
  return __builtin_bit_cast(float, u << 16);
}
__device__ __forceinline__ float bhi(unsigned u) {
  return __builtin_bit_cast(float, u & 0xffff0000u);
}
__device__ __forceinline__ f32x8 unpack8(uint4 u) {
  f32x8 r;
  r[0] = blo(u.x); r[1] = bhi(u.x); r[2] = blo(u.y); r[3] = bhi(u.y);
  r[4] = blo(u.z); r[5] = bhi(u.z); r[6] = blo(u.w); r[7] = bhi(u.w);
  return r;
}
__device__ __forceinline__ uint4 pack8v(const f32x8 o) {
  uint4 s;
  s.x = (unsigned)f2b(o[0]) | ((unsigned)f2b(o[1]) << 16);
  s.y = (unsigned)f2b(o[2]) | ((unsigned)f2b(o[3]) << 16);
  s.z = (unsigned)f2b(o[4]) | ((unsigned)f2b(o[5]) << 16);
  s.w = (unsigned)f2b(o[6]) | ((unsigned)f2b(o[7]) << 16);
  return s;
}
__device__ __forceinline__ void gload16(const void* g, void* l) {
  __builtin_amdgcn_global_load_lds(
      (const __attribute__((address_space(1))) unsigned int*)g,
      (__attribute__((address_space(3))) unsigned int*)l, 16, 0, 0);
}
__device__ __forceinline__ f32x4 mfma16(u16x8 a, u16x8 b, f32x4 c) {
  return __builtin_amdgcn_mfma_f32_16x16x32_bf16(
      __builtin_bit_cast(bf16x8, a), __builtin_bit_cast(bf16x8, b), c, 0, 0, 0);
}
__device__ __forceinline__ void barrier_vm4() {
  asm volatile("s_waitcnt vmcnt(4) lgkmcnt(0)" ::: "memory");
  __builtin_amdgcn_s_barrier();
  asm volatile("" ::: "memory");
}
__device__ __forceinline__ void barrier_vm0() {
  asm volatile("s_waitcnt vmcnt(0) lgkmcnt(0)" ::: "memory");
  __builtin_amdgcn_s_barrier();
  asm volatile("" ::: "memory");
}
__device__ __forceinline__ void fma8(f32x8& a, const f32x8 v, const float4 w0,
                                     const float4 w1) {
  a[0] += v[0] * w0.x; a[1] += v[1] * w0.y;
  a[2] += v[2] * w0.z; a[3] += v[3] * w0.w;
  a[4] += v[4] * w1.x; a[5] += v[5] * w1.y;
  a[6] += v[6] * w1.z; a[7] += v[7] * w1.w;
}

// ------------------------------------------------------------- prep (merged)
__global__ __launch_bounds__(256) void prep_all(
    const float* __restrict__ x, const float* __restrict__ wqkv,
    const float* __restrict__ wproj, bf16* __restrict__ xb,
    bf16* __restrict__ wqkvT, bf16* __restrict__ wprojT) {
  const int bid = blockIdx.x;
  if (bid < 16384) {
    const size_t idx = ((size_t)bid * 256 + threadIdx.x) * 8;
    const float4 a0 = *(const float4*)(x + idx);
    const float4 a1 = *(const float4*)(x + idx + 4);
    u16x8 p;
    p[0] = f2b(a0.x); p[1] = f2b(a0.y); p[2] = f2b(a0.z); p[3] = f2b(a0.w);
    p[4] = f2b(a1.x); p[5] = f2b(a1.y); p[6] = f2b(a1.z); p[7] = f2b(a1.w);
    *(u16x8*)(xb + idx) = p;
  } else {
    const int idx = (bid - 16384) * 256 + threadIdx.x;
    if (idx < 768 * 256) {
      const int j = idx >> 8, k = idx & 255;
      wqkvT[idx] = __float2bfloat16(wqkv[k * 768 + j]);
    }
    if (idx < 256 * 256) {
      const int j = idx >> 8, k = idx & 255;
      wprojT[idx] = __float2bfloat16(wproj[k * 256 + j]);
    }
  }
}

// --------------------------------------------------------------- K1: qkv MFMA
// (R10, frozen)
__global__ __launch_bounds__(256) void qkv_mfma(
    const bf16* __restrict__ xb, const bf16* __restrict__ wT,
    bf16* __restrict__ qO, bf16* __restrict__ kO, bf16* __restrict__ vO) {
  __shared__ __align__(16) char LDSU[49152];
  char* As = LDSU;
  char* Bs = LDSU + 24576;
  const int tid = threadIdx.x;
  const int l = tid & 63, w = tid >> 6;
  const int wr = w >> 1, wc = w & 1;

  const int lin = blockIdx.y * 6 + blockIdx.x;
  const int xcd = lin & 7, qq = lin >> 3;
  const int jt = qq % 6;
  const int ttile = xcd * 128 + qq / 6;
  const int j0 = jt << 7;
  const int t0 = ttile << 7;
  const int b = t0 >> 14;
  const int n0 = t0 & 16383;

  f32x4 acc[4][4];
#pragma unroll
  for (int m = 0; m < 4; ++m)
#pragma unroll
    for (int t = 0; t < 4; ++t) acc[m][t] = (f32x4){0.f, 0.f, 0.f, 0.f};

  const int row0 = w * 16 + (l >> 2), row1 = row0 + 64;
  const int sl = l & 3;
  const int sw0 = (row0 >> 1) & 3, sw1 = (row1 >> 1) & 3;
  const bf16* asrc0 = wT + (size_t)(j0 + row0) * 256 + ((sl ^ sw0) << 3);
  const bf16* asrc1 = wT + (size_t)(j0 + row1) * 256 + ((sl ^ sw1) << 3);
  const bf16* bsrc0 = xb + (size_t)(t0 + row0) * 256 + ((sl ^ sw0) << 3);
  const bf16* bsrc1 = xb + (size_t)(t0 + row1) * 256 + ((sl ^ sw1) << 3);
  const int d0 = w * 1024, d1 = 4096 + w * 1024;

  const int fr = l & 15;
  const int fq = l >> 4;
  const int fs = (fq ^ ((l >> 1) & 3)) << 4;

  gload16(asrc0, As + d0);
  gload16(asrc1, As + d1);
  gload16(bsrc0, Bs + d0);
  gload16(bsrc1, Bs + d1);
  gload16(asrc0 + 32, As + 8192 + d0);
  gload16(asrc1 + 32, As + 8192 + d1);
  gload16(bsrc0 + 32, Bs + 8192 + d0);
  gload16(bsrc1 + 32, Bs + 8192 + d1);
  barrier_vm4();

#pragma unroll
  for (int t = 0; t < 8; ++t) {
    if (t < 6) {
      const int kn = (t + 2) << 5;
      const int nb = ((t + 2) % 3) * 8192;
      gload16(asrc0 + kn, As + nb + d0);
      gload16(asrc1 + kn, As + nb + d1);
      gload16(bsrc0 + kn, Bs + nb + d0);
      gload16(bsrc1 + kn, Bs + nb + d1);
    }
    const char* Ac = As + (t % 3) * 8192;
    const char* Bc = Bs + (t % 3) * 8192;
    u16x8 af[4], bfv[4];
#pragma unroll
    for (int m = 0; m < 4; ++m)
      af[m] = *(const u16x8*)(Ac + (wr * 64 + m * 16 + fr) * 64 + fs);
#pragma unroll
    for (int tt = 0; tt < 4; ++tt)
      bfv[tt] = *(const u16x8*)(Bc + (wc * 64 + tt * 16 + fr) * 64 + fs);
    __builtin_amdgcn_s_setprio(1);
#pragma unroll
    for (int m = 0; m < 4; ++m)
#pragma unroll
      for (int tt = 0; tt < 4; ++tt)
        acc[m][tt] = mfma16(af[m], bfv[tt], acc[m][tt]);
    __builtin_amdgcn_s_setprio(0);
    if (t < 6) barrier_vm4();
    else if (t < 7) barrier_vm0();
  }
  __syncthreads();

#pragma unroll
  for (int m = 0; m < 4; ++m) {
    const int jq = wr * 16 + m * 4 + fq;
#pragma unroll
    for (int t = 0; t < 4; ++t) {
      const int token = wc * 64 + t * 16 + fr;
      const int p = jq ^ (token & 15);
      uint2 pk;
      pk.x = (unsigned)f2b(acc[m][t][0]) | ((unsigned)f2b(acc[m][t][1]) << 16);
      pk.y = (unsigned)f2b(acc[m][t][2]) | ((unsigned)f2b(acc[m][t][3]) << 16);
      *(uint2*)(LDSU + token * 256 + (p << 3)) = pk;
    }
  }
  __syncthreads();

  const int region = j0 >> 8;
  bf16* outp = (region == 0) ? qO : ((region == 1) ? kO : vO);
  const int jl = j0 & 255;
  const int seg = tid & 15;
#pragma unroll
  for (int r = 0; r < 8; ++r) {
    const int token = r * 16 + (tid >> 4);
    const int tsw = token & 15;
    const uint2 lo = *(const uint2*)(LDSU + token * 256 + (((2 * seg) ^ tsw) << 3));
    const uint2 hi =
        *(const uint2*)(LDSU + token * 256 + (((2 * seg + 1) ^ tsw) << 3));
    uint4 d;
    d.x = lo.x; d.y = lo.y; d.z = hi.x; d.w = hi.y;
    *(uint4*)&outp[((size_t)b * 16384 + n0 + token) * 256 + jl + seg * 8] = d;
  }
}

// ----------------------------------------------- K1b: kv reduce (two-stage)
// Stage 1: grid (64, 8), 256 tokens/block, non-atomic partials write.
__global__ __launch_bounds__(256) void kv_reduce1(
    const bf16* __restrict__ kT, const bf16* __restrict__ vT,
    float* __restrict__ kvpart) {
  __shared__ float red[256 * 8];
  const int tid = threadIdx.x;
  const int b = blockIdx.y;
  const int seg = tid & 31;
  f32x8 part = (f32x8)0.f;

  for (int r = 0; r < 32; ++r) {
    const int token = blockIdx.x * 256 + r * 8 + (tid >> 5);
    const size_t roff = ((size_t)b * 16384 + token) * 256;
    const uint4 kd = *(const uint4*)(kT + roff + seg * 8);
    const f32x8 kf = unpack8(kd);
    float ss = 0.f;
#pragma unroll
    for (int i = 0; i < 8; ++i) ss += kf[i] * kf[i];
    ss += __shfl_xor(ss, 1);
    ss += __shfl_xor(ss, 2);
    const float inv = rsqrtf(ss);
    const uint4 vd = *(const uint4*)(vT + roff + seg * 8);
    const f32x8 vf = unpack8(vd);
#pragma unroll
    for (int i = 0; i < 8; ++i) part[i] += kf[i] * inv * vf[i];
  }
#pragma unroll
  for (int i = 0; i < 8; ++i) red[tid * 8 + i] = part[i];
  __syncthreads();
  if (tid < 32) {
    f32x8 s = (f32x8)0.f;
#pragma unroll
    for (int k = 0; k < 8; ++k)
#pragma unroll
      for (int i = 0; i < 8; ++i) s[i] += red[(tid + 32 * k) * 8 + i];
    float* dst = kvpart + ((size_t)b * 64 + blockIdx.x) * 256 + tid * 8;
#pragma unroll
    for (int i = 0; i < 8; ++i) dst[i] = s[i];
  }
}

// Stage 2: grid (8), 256 threads; thread = channel, sum 64 partials.
__global__ __launch_bounds__(256) void kv_reduce2(
    const float* __restrict__ kvpart, float* __restrict__ kv) {
  const int b = blockIdx.x;
  const int c = threadIdx.x;
  float s = 0.f;
  const float* src = kvpart + (size_t)b * 64 * 256 + c;
#pragma unroll 8
  for (int k = 0; k < 64; ++k) s += src[k * 256];
  kv[b * 256 + c] = s;
}

// ------------------------------------------------- K2: crpe conv + combine
// (R8/R10: 32x16 tile, 2px/thread rolling-register conv, plane-per-cc LDS,
//  direct per-lane uint4 stores — 4 back-to-back 16B fills a 64B line)
template <int K>
__global__ __launch_bounds__(256) void crpe_conv(
    const bf16* __restrict__ qT, const bf16* __restrict__ vT,
    const float* __restrict__ kvbuf, const float* __restrict__ wp,
    const float* __restrict__ bp, int OC, int hbase,
    bf16* __restrict__ mid) {
  constexpr int R = K / 2;
  constexpr int SY = 16 + 2 * R;
  constexpr int SXr = 32 + 2 * R;
  constexpr int SX = SXr + 1;
  constexpr int PL = SX * SY;
  __shared__ __align__(16) uint4 vs[4 * PL];
  __shared__ float wlds[K * K * 32];
  __shared__ float blds[32];

  const int tid = threadIdx.x;
  const int hg = blockIdx.x;
  const int h = hbase + hg;
  const int tile = blockIdx.y;
  const int b = blockIdx.z;
  const int tx0 = (tile & 3) * 32, ty0 = (tile >> 2) * 16;
  const int tx = tid & 15, ty = tid >> 4;
  const int ocbase = hg * 32;

  {
    const int cc = tid & 3;
    for (int e = tid >> 2; e < SXr * SY; e += 64) {
      const int ly = e / SXr, lx = e - ly * SXr;
      const int gy = ty0 - R + ly, gx = tx0 - R + lx;
      uint4 d = {0, 0, 0, 0};
      if (gy >= 0 && gy < 128 && gx >= 0 && gx < 128)
        d = *((const uint4*)(vT + ((size_t)b * 16384 + gy * 128 + gx) * 256 +
                             h * 32) + cc);
      vs[cc * PL + ly * SX + lx] = d;
    }
  }
  for (int e = tid; e < K * K * 32; e += 256)
    wlds[e] = wp[(e >> 5) * OC + ocbase + (e & 31)];
  if (tid < 32) blds[tid] = bp[ocbase + tid];
  __syncthreads();

  const int n = (ty0 + ty) * 128 + tx0 + 2 * tx;
  const size_t off0 = ((size_t)b * 16384 + n) * 256 + h * 32;
  const uint4* q0 = (const uint4*)(qT + off0);
  const uint4* q1 = (const uint4*)(qT + off0 + 256);
  float ss0 = 0.f, ss1 = 0.f;
#pragma unroll
  for (int cc = 0; cc < 4; ++cc) {
    const f32x8 a = unpack8(q0[cc]);
    const f32x8 c = unpack8(q1[cc]);
#pragma unroll
    for (int i = 0; i < 8; ++i) { ss0 += a[i] * a[i]; ss1 += c[i] * c[i]; }
  }
  const float qinv0 = rsqrtf(ss0), qinv1 = rsqrtf(ss1);
  const float4* kvp = (const float4*)(kvbuf + ((size_t)b * 8 + h) * 32);
  const float4* wlds4 = (const float4*)wlds;
  const float4* bl4 = (const float4*)blds;
  uint4* m0 = (uint4*)(mid + off0);
  uint4* m1 = (uint4*)(mid + off0 + 256);

#pragma unroll 1
  for (int cc = 0; cc < 4; ++cc) {
    const uint4* vplane = vs + cc * PL;
    const float4 ba = bl4[cc * 2], bb = bl4[cc * 2 + 1];
    f32x8 a0, a1;
    a0[0] = ba.x; a0[1] = ba.y; a0[2] = ba.z; a0[3] = ba.w;
    a0[4] = bb.x; a0[5] = bb.y; a0[6] = bb.z; a0[7] = bb.w;
    a1 = a0;
#pragma unroll
    for (int ky = 0; ky < K; ++ky) {
      const uint4* vrow = vplane + (ty + ky) * SX + 2 * tx;
      f32x8 vcur = unpack8(vrow[0]);
#pragma unroll
      for (int kx = 0; kx < K; ++kx) {
        const f32x8 vnx = unpack8(vrow[kx + 1]);
        const float4 w0 = wlds4[(ky * K + kx) * 8 + cc * 2];
        const float4 w1 = wlds4[(ky * K + kx) * 8 + cc * 2 + 1];
        fma8(a0, vcur, w0, w1);
        fma8(a1, vnx, w0, w1);
        vcur = vnx;
      }
    }
    const float4 ka = kvp[cc * 2], kb = kvp[cc * 2 + 1];
    f32x8 kvf;
    kvf[0] = ka.x; kvf[1] = ka.y; kvf[2] = ka.z; kvf[3] = ka.w;
    kvf[4] = kb.x; kvf[5] = kb.y; kvf[6] = kb.z; kvf[7] = kb.w;
    {
      const f32x8 qv = unpack8(q0[cc]);
      f32x8 o;
#pragma unroll
      for (int i = 0; i < 8; ++i)
        o[i] = SCALE_ * qv[i] * qinv0 * kvf[i] + qv[i] * a0[i];
      m0[cc] = pack8v(o);
    }
    {
      const f32x8 qv = unpack8(q1[cc]);
      f32x8 o;
#pragma unroll
      for (int i = 0; i < 8; ++i)
        o[i] = SCALE_ * qv[i] * qinv1 * kvf[i] + qv[i] * a1[i];
      m1[cc] = pack8v(o);
    }
  }
}

// --------------------------------------------------------------- K3: proj MFMA
// (R10, frozen)
__global__ __launch_bounds__(256) void proj_mfma(
    const bf16* __restrict__ mid, const bf16* __restrict__ wpT,
    const float* __restrict__ bproj, float* __restrict__ out) {
  __shared__ __align__(16) char LDSU[49152];
  char* As = LDSU;
  char* Bs = LDSU + 24576;
  const int tid = threadIdx.x;
  const int l = tid & 63, w = tid >> 6;
  const int wr = w >> 1, wc = w & 1;

  const int lin = blockIdx.y * 2 + blockIdx.x;
  const int xcd = lin & 7, qq = lin >> 3;
  const int jt = qq & 1;
  const int ttile = xcd * 128 + (qq >> 1);
  const int j0 = jt << 7;
  const int tk0 = ttile << 7;

  f32x4 acc[4][4];
#pragma unroll
  for (int m = 0; m < 4; ++m)
#pragma unroll
    for (int t = 0; t < 4; ++t) acc[m][t] = (f32x4){0.f, 0.f, 0.f, 0.f};

  const int row0 = w * 16 + (l >> 2), row1 = row0 + 64;
  const int sl = l & 3;
  const int sw0 = (row0 >> 1) & 3, sw1 = (row1 >> 1) & 3;
  const bf16* asrc0 = wpT + (size_t)(j0 + row0) * 256 + ((sl ^ sw0) << 3);
  const bf16* asrc1 = wpT + (size_t)(j0 + row1) * 256 + ((sl ^ sw1) << 3);
  const bf16* bsrc0 = mid + (size_t)(tk0 + row0) * 256 + ((sl ^ sw0) << 3);
  const bf16* bsrc1 = mid + (size_t)(tk0 + row1) * 256 + ((sl ^ sw1) << 3);
  const int d0 = w * 1024, d1 = 4096 + w * 1024;

  const int fr = l & 15;
  const int fq = l >> 4;
  const int fs = (fq ^ ((l >> 1) & 3)) << 4;

  gload16(asrc0, As + d0);
  gload16(asrc1, As + d1);
  gload16(bsrc0, Bs + d0);
  gload16(bsrc1, Bs + d1);
  gload16(asrc0 + 32, As + 8192 + d0);
  gload16(asrc1 + 32, As + 8192 + d1);
  gload16(bsrc0 + 32, Bs + 8192 + d0);
  gload16(bsrc1 + 32, Bs + 8192 + d1);
  barrier_vm4();

#pragma unroll
  for (int t = 0; t < 8; ++t) {
    if (t < 6) {
      const int kn = (t + 2) << 5;
      const int nb = ((t + 2) % 3) * 8192;
      gload16(asrc0 + kn, As + nb + d0);
      gload16(asrc1 + kn, As + nb + d1);
      gload16(bsrc0 + kn, Bs + nb + d0);
      gload16(bsrc1 + kn, Bs + nb + d1);
    }
    const char* Ac = As + (t % 3) * 8192;
    const char* Bc = Bs + (t % 3) * 8192;
    u16x8 af[4], bfv[4];
#pragma unroll
    for (int m = 0; m < 4; ++m)
      af[m] = *(const u16x8*)(Ac + (wr * 64 + m * 16 + fr) * 64 + fs);
#pragma unroll
    for (int tt = 0; tt < 4; ++tt)
      bfv[tt] = *(const u16x8*)(Bc + (wc * 64 + tt * 16 + fr) * 64 + fs);
    __builtin_amdgcn_s_setprio(1);
#pragma unroll
    for (int m = 0; m < 4; ++m)
#pragma unroll
      for (int tt = 0; tt < 4; ++tt)
        acc[m][tt] = mfma16(af[m], bfv[tt], acc[m][tt]);
    __builtin_amdgcn_s_setprio(0);
    if (t < 6) barrier_vm4();
    else if (t < 7) barrier_vm0();
  }
  __syncthreads();

#pragma unroll
  for (int m = 0; m < 4; ++m) {
    const float4 bias = *(const float4*)&bproj[j0 + wr * 64 + m * 16 + fq * 4];
#pragma unroll
    for (int t = 0; t < 4; ++t) {
      acc[m][t][0] += bias.x;
      acc[m][t][1] += bias.y;
      acc[m][t][2] += bias.z;
      acc[m][t][3] += bias.w;
    }
  }

  for (int chunk = 0; chunk < 2; ++chunk) {
    if (wc == chunk) {
#pragma unroll
      for (int m = 0; m < 4; ++m) {
        const int jq = wr * 16 + m * 4 + fq;
#pragma unroll
        for (int t = 0; t < 4; ++t) {
          const int ltok = t * 16 + fr;
          const int p = jq ^ (ltok & 15);
          float4 r;
          r.x = acc[m][t][0]; r.y = acc[m][t][1];
          r.z = acc[m][t][2]; r.w = acc[m][t][3];
          *(float4*)(LDSU + ltok * 512 + (p << 4)) = r;
        }
      }
    }
    __syncthreads();
    const int seg = tid & 31;
#pragma unroll
    for (int r = 0; r < 8; ++r) {
      const int ltok = r * 8 + (tid >> 5);
      const int p = seg ^ (ltok & 15);
      const float4 dv = *(const float4*)(LDSU + ltok * 512 + (p << 4));
      *(float4*)&out[(size_t)(tk0 + chunk * 64 + ltok) * 256 + j0 + seg * 4] = dv;
    }
    __syncthreads();
  }
}

// ------------------------------------------------------------------- launcher
extern "C" void kernel_launch(void* const* d_in, const int* in_sizes, int n_in,
                              void* d_out, int out_size, void* d_ws,
                              size_t ws_size, hipStream_t stream) {
  const float* x     = (const float*)d_in[0];
  const float* wqkv  = (const float*)d_in[1];
  const float* wproj = (const float*)d_in[2];
  const float* bproj = (const float*)d_in[3];
  const float* w3 = (const float*)d_in[4];
  const float* b3 = (const float*)d_in[5];
  const float* w5 = (const float*)d_in[6];
  const float* b5 = (const float*)d_in[7];
  const float* w7 = (const float*)d_in[8];
  const float* b7 = (const float*)d_in[9];
  float* out = (float*)d_out;

  const size_t PLANE = (size_t)8 * 16384 * 256;
  bf16* qT  = (bf16*)d_ws;
  bf16* vT  = qT + PLANE;
  bf16* kT  = vT + PLANE;
  bf16* mid = kT;                     // alias: k dead after kv_reduce
  float* kv = (float*)(kT + PLANE);
  bf16* wqkvT  = (bf16*)(kv + 2048);
  bf16* wprojT = wqkvT + 768 * 256;
  bf16* xb = (bf16*)d_out;            // d_out bytes [0, 64MB): xb scratch
  float* kvpart = out + 16777216;     // d_out bytes [64MB, 64.5MB): partials

  prep_all<<<dim3(16384 + 768), 256, 0, stream>>>(x, wqkv, wproj, xb, wqkvT,
                                                  wprojT);
  qkv_mfma<<<dim3(6, 1024), 256, 0, stream>>>(xb, wqkvT, qT, kT, vT);
  kv_reduce1<<<dim3(64, 8), 256, 0, stream>>>(kT, vT, kvpart);
  kv_reduce2<<<dim3(8), 256, 0, stream>>>(kvpart, kv);
  crpe_conv<3><<<dim3(2, 32, 8), 256, 0, stream>>>(qT, vT, kv, w3, b3, 64, 0, mid);
  crpe_conv<5><<<dim3(3, 32, 8), 256, 0, stream>>>(qT, vT, kv, w5, b5, 96, 2, mid);
  crpe_conv<7><<<dim3(3, 32, 8), 256, 0, stream>>>(qT, vT, kv, w7, b7, 96, 5, mid);
  proj_mfma<<<dim3(2, 1024), 256, 0, stream>>>(mid, wprojT, bproj, out);
}